// Round 7
// baseline (591.739 us; speedup 1.0000x reference)
//
#include <hip/hip_runtime.h>
#include <math.h>

#define NEG_SLOPE 0.2f
#define FIN 128
#define H1 8
#define F1 64   // HEADS1*HID
#define F2 32   // OUT2

#define SHIFT 6
#define BW 64          // dsts per bucket
#define CAP 4096       // max edges per bucket in LDS (avg ~2112, sigma ~46)
#define NBMAX 2048

typedef unsigned short ushort_t;
typedef unsigned int uint_t;

static __device__ __forceinline__ ushort_t f2bf(float f) {
    uint_t u = __float_as_uint(f);
    u = (u + 0x7FFFu + ((u >> 16) & 1u)) >> 16; // RNE
    return (ushort_t)u;
}
static __device__ __forceinline__ float bf2f(ushort_t h) {
    return __uint_as_float(((uint_t)h) << 16);
}
// pack {A=exp(e), B=exp(0.2e)} as bf16x2: A in low 16, B in high 16
static __device__ __forceinline__ uint_t packAB(float e) {
    return (uint_t)f2bf(__expf(e)) | ((uint_t)f2bf(__expf(NEG_SLOPE * e)) << 16);
}

// ---------------- Layer-1 GEMM: h1 = x @ W1 (bf16 out), fused exp-tables -----
__global__ void gemm1_kernel(const float* __restrict__ x, const float* __restrict__ W1,
                             const float* __restrict__ a_src, const float* __restrict__ a_dst,
                             ushort_t* __restrict__ h1, uint_t* __restrict__ sp,
                             float* __restrict__ ed, int N) {
    int w = threadIdx.x >> 6;
    int j = threadIdx.x & 63;
    int n = blockIdx.x * 4 + w;
    __shared__ float xs[4][FIN];
    if (n < N) {
        xs[w][j]      = x[(size_t)n * FIN + j];
        xs[w][j + 64] = x[(size_t)n * FIN + 64 + j];
    }
    // wave-synchronous LDS (same wave writes & reads)
    if (n >= N) return;
    float acc = 0.f;
#pragma unroll
    for (int k = 0; k < FIN; ++k) acc = fmaf(xs[w][k], W1[k * F1 + j], acc);
    h1[(size_t)n * F1 + j] = f2bf(acc);
    float vs = acc * a_src[j];
    float vd = acc * a_dst[j];
#pragma unroll
    for (int off = 4; off >= 1; off >>= 1) {
        vs += __shfl_down(vs, off, 8);
        vd += __shfl_down(vd, off, 8);
    }
    if ((j & 7) == 0) {
        sp[n * H1 + (j >> 3)] = packAB(vs);   // src-side exp table (bf16x2)
        ed[n * H1 + (j >> 3)] = vd;           // raw dst logit
    }
}

// ---------------- bucket CSR build ------------------------------------------
__global__ void zerob_kernel(int* __restrict__ bcnt, int NB, float* __restrict__ pooled) {
    int t = blockIdx.x * blockDim.x + threadIdx.x;
    int stride = gridDim.x * blockDim.x;
    for (int i = t; i < NB; i += stride) bcnt[i] = 0;
    if (t == 0) pooled[0] = 0.f;
}

__global__ void bhist_kernel(const int* __restrict__ ei, int E, int N,
                             int* __restrict__ bcnt, int NB) {
    __shared__ int h[NBMAX];
    int tid = threadIdx.x;
    for (int i = tid; i < NB; i += 256) h[i] = 0;
    __syncthreads();
    int EN = E + N;
    int chunk = (EN + gridDim.x - 1) / gridDim.x;
    int e0 = blockIdx.x * chunk;
    int e1 = e0 + chunk; if (e1 > EN) e1 = EN;
    for (int t = e0 + tid; t < e1; t += 256) {
        int d = (t < E) ? ei[E + t] : (t - E);
        atomicAdd(&h[d >> SHIFT], 1);
    }
    __syncthreads();
    for (int i = tid; i < NB; i += 256)
        if (h[i]) atomicAdd(&bcnt[i], h[i]);
}

__global__ void bscan_kernel(const int* __restrict__ bcnt, int NB,
                             int* __restrict__ boff, int* __restrict__ bcur) {
    int lane = threadIdx.x; // 0..63
    int chunk = (NB + 63) >> 6;
    int lo = lane * chunk;
    int hi = lo + chunk; if (hi > NB) hi = NB;
    int sum = 0;
    for (int i = lo; i < hi; ++i) sum += bcnt[i];
    int e = sum;
#pragma unroll
    for (int o = 1; o < 64; o <<= 1) {
        int v = __shfl_up(e, o, 64);
        if (lane >= o) e += v;
    }
    e -= sum;
    int run = e;
    for (int i = lo; i < hi; ++i) {
        int c = bcnt[i];
        boff[i] = run;
        bcur[i] = run;
        run += c;
    }
}

__global__ void bscat_kernel(const int* __restrict__ ei, int E, int N,
                             int* __restrict__ bcur, uint_t* __restrict__ pk, int NB) {
    __shared__ int lh[NBMAX];
    __shared__ int lc[NBMAX];
    int tid = threadIdx.x;
    for (int i = tid; i < NB; i += 256) lh[i] = 0;
    __syncthreads();
    int EN = E + N;
    int chunk = (EN + gridDim.x - 1) / gridDim.x;
    int e0 = blockIdx.x * chunk;
    int e1 = e0 + chunk; if (e1 > EN) e1 = EN;
    for (int t = e0 + tid; t < e1; t += 256) {
        int d = (t < E) ? ei[E + t] : (t - E);
        atomicAdd(&lh[d >> SHIFT], 1);
    }
    __syncthreads();
    for (int i = tid; i < NB; i += 256) {
        int c = lh[i];
        lc[i] = c ? atomicAdd(&bcur[i], c) : 0;
    }
    __syncthreads();
    for (int t = e0 + tid; t < e1; t += 256) {
        int s, d;
        if (t < E) { s = ei[t]; d = ei[E + t]; } else { s = d = t - E; }
        int pos = atomicAdd(&lc[d >> SHIFT], 1);
        pk[pos] = ((uint_t)s << SHIFT) | (uint_t)(d & (BW - 1));
    }
}

// ---------------- Layer-1 edge pass: 4 edges/iter, 4 channels/lane -----------
// one block per bucket; wave per dst (16 dsts/wave). Lane L: edge slot q=L>>4,
// channels c4=(L&15)*4 (one dwordx2 = 4 bf16), head (L&15)>>1.
__global__ void edge1_gather(const int* __restrict__ bcnt, const int* __restrict__ boff,
                             const uint_t* __restrict__ pk,
                             const uint_t* __restrict__ sp, const float* __restrict__ ed,
                             const ushort_t* __restrict__ h1, float* __restrict__ o1, int N) {
    int b = blockIdx.x;
    int d0 = b << SHIFT;
    int cnt = bcnt[b];
    int gbase = boff[b];
    int tid = threadIdx.x;
    int wv = tid >> 6;
    int L = tid & 63;
    int q = L >> 4;           // edge slot 0..3
    int c4 = (L & 15) << 2;   // channel base
    int hL = (L & 15) >> 1;   // head of channels c4..c4+3
    __shared__ int ldeg[BW];
    __shared__ int loff[BW];
    __shared__ int lcur[BW];
    __shared__ int lsrc[CAP];
    if (cnt <= CAP) {
        if (tid < BW) ldeg[tid] = 0;
        __syncthreads();
        for (int k = tid; k < cnt; k += 256) atomicAdd(&ldeg[pk[gbase + k] & (BW - 1)], 1);
        __syncthreads();
        if (tid < 64) {
            int v = ldeg[tid];
            int e = v;
#pragma unroll
            for (int o = 1; o < 64; o <<= 1) {
                int u = __shfl_up(e, o, 64);
                if (tid >= o) e += u;
            }
            e -= v;
            loff[tid] = e;
            lcur[tid] = e;
        }
        __syncthreads();
        for (int k = tid; k < cnt; k += 256) {
            uint_t v = pk[gbase + k];
            int pos = atomicAdd(&lcur[v & (BW - 1)], 1);
            lsrc[pos] = (int)(v >> SHIFT);
        }
        __syncthreads();
        for (int ld = wv * 16; ld < wv * 16 + 16; ++ld) {
            int d = d0 + ld;
            if (d >= N) break;
            int st = loff[ld], en = st + ldeg[ld];
            float edv = ed[d * H1 + hL];
            float Ad = __expf(edv), Bd = __expf(NEG_SLOPE * edv);
            float ax = 0.f, ay = 0.f, az = 0.f, aw = 0.f, wsum = 0.f;
            for (int k = st; k < en; k += 4) {
                int idx = k + q;
                bool ok = idx < en;
                int s = lsrc[ok ? idx : st];   // st valid: self-loop => en>st
                uint_t u = sp[(uint_t)s * H1 + hL];
                float w = ok ? fmaxf(__uint_as_float(u << 16) * Ad,
                                     __uint_as_float(u & 0xffff0000u) * Bd) : 0.f;
                uint2 hv = *(const uint2*)(h1 + ((uint_t)s << 6) + c4);
                ax = fmaf(w, __uint_as_float(hv.x << 16), ax);
                ay = fmaf(w, __uint_as_float(hv.x & 0xffff0000u), ay);
                az = fmaf(w, __uint_as_float(hv.y << 16), az);
                aw = fmaf(w, __uint_as_float(hv.y & 0xffff0000u), aw);
                wsum += w;
            }
            // fold the 4 edge slots (lanes differing in bits 4..5)
            ax += __shfl_xor(ax, 16, 64); ax += __shfl_xor(ax, 32, 64);
            ay += __shfl_xor(ay, 16, 64); ay += __shfl_xor(ay, 32, 64);
            az += __shfl_xor(az, 16, 64); az += __shfl_xor(az, 32, 64);
            aw += __shfl_xor(aw, 16, 64); aw += __shfl_xor(aw, 32, 64);
            wsum += __shfl_xor(wsum, 16, 64); wsum += __shfl_xor(wsum, 32, 64);
            if (q == 0) {
                float inv = 1.f / wsum;
                float4 r; r.x = ax * inv; r.y = ay * inv; r.z = az * inv; r.w = aw * inv;
                *(float4*)(o1 + (size_t)d * F1 + c4) = r;
            }
        }
    } else {
        // statistically unreachable fallback: scan whole bucket per dst
        for (int ld = wv * 16; ld < wv * 16 + 16; ++ld) {
            int d = d0 + ld;
            if (d >= N) break;
            float edv = ed[d * H1 + hL];
            float Ad = __expf(edv), Bd = __expf(NEG_SLOPE * edv);
            float ax = 0.f, ay = 0.f, az = 0.f, aw = 0.f, wsum = 0.f;
            for (int k0 = 0; k0 < cnt; k0 += 4) {
                int idx = k0 + q;
                bool ok = idx < cnt;
                uint_t v = pk[gbase + (ok ? idx : 0)];
                int s = (int)(v >> SHIFT);
                bool m = ok && ((int)(v & (BW - 1)) == ld);
                uint_t u = sp[(uint_t)s * H1 + hL];
                float w = m ? fmaxf(__uint_as_float(u << 16) * Ad,
                                    __uint_as_float(u & 0xffff0000u) * Bd) : 0.f;
                uint2 hv = *(const uint2*)(h1 + ((uint_t)s << 6) + c4);
                ax = fmaf(w, __uint_as_float(hv.x << 16), ax);
                ay = fmaf(w, __uint_as_float(hv.x & 0xffff0000u), ay);
                az = fmaf(w, __uint_as_float(hv.y << 16), az);
                aw = fmaf(w, __uint_as_float(hv.y & 0xffff0000u), aw);
                wsum += w;
            }
            ax += __shfl_xor(ax, 16, 64); ax += __shfl_xor(ax, 32, 64);
            ay += __shfl_xor(ay, 16, 64); ay += __shfl_xor(ay, 32, 64);
            az += __shfl_xor(az, 16, 64); az += __shfl_xor(az, 32, 64);
            aw += __shfl_xor(aw, 16, 64); aw += __shfl_xor(aw, 32, 64);
            wsum += __shfl_xor(wsum, 16, 64); wsum += __shfl_xor(wsum, 32, 64);
            if (q == 0) {
                float inv = 1.f / wsum;
                float4 r; r.x = ax * inv; r.y = ay * inv; r.z = az * inv; r.w = aw * inv;
                *(float4*)(o1 + (size_t)d * F1 + c4) = r;
            }
        }
    }
}

// ---------------- Layer-2 GEMM: a1 = elu(o1 + b1); h2 = a1 @ W2 (bf16) -------
__global__ void gemm2_kernel(const float* __restrict__ o1, const float* __restrict__ b1,
                             const float* __restrict__ W2,
                             const float* __restrict__ a_src2, const float* __restrict__ a_dst2,
                             ushort_t* __restrict__ h2, uint_t* __restrict__ sp2,
                             float* __restrict__ ed2, int N) {
    int half = threadIdx.x >> 5;
    int n = blockIdx.x * 8 + half;
    int j = threadIdx.x & 31;
    __shared__ float a1s[8][F1];
    if (n < N) {
#pragma unroll
        for (int r = 0; r < 2; ++r) {
            int k = r * 32 + j;
            float v = o1[(size_t)n * F1 + k] + b1[k];
            a1s[half][k] = v > 0.f ? v : expm1f(v); // ELU
        }
    }
    __syncthreads();
    if (n >= N) return;
    float acc = 0.f;
#pragma unroll
    for (int k = 0; k < F1; ++k) acc = fmaf(a1s[half][k], W2[k * F2 + j], acc);
    h2[(size_t)n * F2 + j] = f2bf(acc);
    float vs = acc * a_src2[j];
    float vd = acc * a_dst2[j];
#pragma unroll
    for (int off = 16; off >= 1; off >>= 1) {
        vs += __shfl_down(vs, off, 32);
        vd += __shfl_down(vd, off, 32);
    }
    if (j == 0) {
        sp2[n] = packAB(vs);
        ed2[n] = vd;
    }
}

// ---------------- Layer-2 edge pass: 4 edges/iter, 2 ch/lane, fused pool·Wr --
// wave per dst (16 dsts/wave). Lane L: edge slot q=L>>4, channels c2=(L&15)*2.
__global__ void edge2_gather(const int* __restrict__ bcnt, const int* __restrict__ boff,
                             const uint_t* __restrict__ pk,
                             const uint_t* __restrict__ sp2, const float* __restrict__ ed2,
                             const ushort_t* __restrict__ h2,
                             const float* __restrict__ b2, const float* __restrict__ Wr,
                             float* __restrict__ pooled, int N) {
    int b = blockIdx.x;
    int d0 = b << SHIFT;
    int cnt = bcnt[b];
    int gbase = boff[b];
    int tid = threadIdx.x;
    int wv = tid >> 6;
    int L = tid & 63;
    int q = L >> 4;
    int c2 = (L & 15) << 1;
    __shared__ int ldeg[BW];
    __shared__ int loff[BW];
    __shared__ int lcur[BW];
    __shared__ int lsrc[CAP];
    float wrx = Wr[c2], wry = Wr[c2 + 1];
    float b2w = b2[c2] * wrx + b2[c2 + 1] * wry;
    float part = 0.f;
    if (cnt <= CAP) {
        if (tid < BW) ldeg[tid] = 0;
        __syncthreads();
        for (int k = tid; k < cnt; k += 256) atomicAdd(&ldeg[pk[gbase + k] & (BW - 1)], 1);
        __syncthreads();
        if (tid < 64) {
            int v = ldeg[tid];
            int e = v;
#pragma unroll
            for (int o = 1; o < 64; o <<= 1) {
                int u = __shfl_up(e, o, 64);
                if (tid >= o) e += u;
            }
            e -= v;
            loff[tid] = e;
            lcur[tid] = e;
        }
        __syncthreads();
        for (int k = tid; k < cnt; k += 256) {
            uint_t v = pk[gbase + k];
            int pos = atomicAdd(&lcur[v & (BW - 1)], 1);
            lsrc[pos] = (int)(v >> SHIFT);
        }
        __syncthreads();
        for (int ld = wv * 16; ld < wv * 16 + 16; ++ld) {
            int d = d0 + ld;
            if (d >= N) break;
            int st = loff[ld], en = st + ldeg[ld];
            float edv = ed2[d];
            float Ad = __expf(edv), Bd = __expf(NEG_SLOPE * edv);
            float ax = 0.f, ay = 0.f, wsum = 0.f;
            for (int k = st; k < en; k += 4) {
                int idx = k + q;
                bool ok = idx < en;
                int s = lsrc[ok ? idx : st];
                uint_t u = sp2[s];
                float w = ok ? fmaxf(__uint_as_float(u << 16) * Ad,
                                     __uint_as_float(u & 0xffff0000u) * Bd) : 0.f;
                uint_t hv = *(const uint_t*)(h2 + ((uint_t)s << 5) + c2);
                ax = fmaf(w, __uint_as_float(hv << 16), ax);
                ay = fmaf(w, __uint_as_float(hv & 0xffff0000u), ay);
                wsum += w;
            }
            ax += __shfl_xor(ax, 16, 64); ax += __shfl_xor(ax, 32, 64);
            ay += __shfl_xor(ay, 16, 64); ay += __shfl_xor(ay, 32, 64);
            wsum += __shfl_xor(wsum, 16, 64); wsum += __shfl_xor(wsum, 32, 64);
            if (q == 0) {
                float inv = 1.f / wsum;
                part += fmaf(ax * inv, wrx, fmaf(ay * inv, wry, b2w));
            }
        }
    } else {
        for (int ld = wv * 16; ld < wv * 16 + 16; ++ld) {
            int d = d0 + ld;
            if (d >= N) break;
            float edv = ed2[d];
            float Ad = __expf(edv), Bd = __expf(NEG_SLOPE * edv);
            float ax = 0.f, ay = 0.f, wsum = 0.f;
            for (int k0 = 0; k0 < cnt; k0 += 4) {
                int idx = k0 + q;
                bool ok = idx < cnt;
                uint_t v = pk[gbase + (ok ? idx : 0)];
                int s = (int)(v >> SHIFT);
                bool m = ok && ((int)(v & (BW - 1)) == ld);
                uint_t u = sp2[s];
                float w = m ? fmaxf(__uint_as_float(u << 16) * Ad,
                                    __uint_as_float(u & 0xffff0000u) * Bd) : 0.f;
                uint_t hv = *(const uint_t*)(h2 + ((uint_t)s << 5) + c2);
                ax = fmaf(w, __uint_as_float(hv << 16), ax);
                ay = fmaf(w, __uint_as_float(hv & 0xffff0000u), ay);
                wsum += w;
            }
            ax += __shfl_xor(ax, 16, 64); ax += __shfl_xor(ax, 32, 64);
            ay += __shfl_xor(ay, 16, 64); ay += __shfl_xor(ay, 32, 64);
            wsum += __shfl_xor(wsum, 16, 64); wsum += __shfl_xor(wsum, 32, 64);
            if (q == 0) {
                float inv = 1.f / wsum;
                part += fmaf(ax * inv, wrx, fmaf(ay * inv, wry, b2w));
            }
        }
    }
    // block reduction -> one atomic
#pragma unroll
    for (int o = 32; o >= 1; o >>= 1) part += __shfl_down(part, o, 64);
    __shared__ float ls[4];
    int wave = tid >> 6;
    if ((tid & 63) == 0) ls[wave] = part;
    __syncthreads();
    if (tid == 0) atomicAdd(pooled, ls[0] + ls[1] + ls[2] + ls[3]);
}

__global__ void final_kernel(const float* __restrict__ pooled, const float* __restrict__ br,
                             float* __restrict__ out) {
    if (threadIdx.x == 0 && blockIdx.x == 0) out[0] = pooled[0] + br[0];
}

extern "C" void kernel_launch(void* const* d_in, const int* in_sizes, int n_in,
                              void* d_out, int out_size, void* d_ws, size_t ws_size,
                              hipStream_t stream) {
    const float* x    = (const float*)d_in[0];
    const int*   ei   = (const int*)d_in[1];
    const float* W1   = (const float*)d_in[2];
    const float* a_s1 = (const float*)d_in[3];
    const float* a_d1 = (const float*)d_in[4];
    const float* b1   = (const float*)d_in[5];
    const float* W2   = (const float*)d_in[6];
    const float* a_s2 = (const float*)d_in[7];
    const float* a_d2 = (const float*)d_in[8];
    const float* b2   = (const float*)d_in[9];
    const float* Wr   = (const float*)d_in[10];
    const float* br   = (const float*)d_in[11];
    float* out = (float*)d_out;

    int N = in_sizes[0] / FIN;
    int E = in_sizes[1] / 2;
    size_t n = (size_t)N;
    int NB = (N + BW - 1) >> SHIFT;

    // workspace layout (bytes), total ~= 58 MB for N=100k, E=3.2M
    char* ws = (char*)d_ws;
    float*    o1   = (float*)ws;                          // 64N f32
    uint_t*   sp1  = (uint_t*)(ws + n * 256);             // 8N u32 (bf16x2 exp table)
    float*    ed1  = (float*)(ws + n * 288);              // 8N f32
    ushort_t* h1   = (ushort_t*)(ws + n * 320);           // 64N bf16
    uint_t*   pk   = (uint_t*)(ws + n * 448);             // (E+N) uint
    char*     tail = ws + n * 448 + (size_t)(E + N) * 4;
    int*      bcnt = (int*)tail;                          // NBMAX int
    int*      boff = (int*)(tail + NBMAX * 4);            // NBMAX int
    int*      bcur = (int*)(tail + NBMAX * 8);            // NBMAX int
    float*  pooled = (float*)(tail + NBMAX * 12);         // 1 f32
    // layer-2 overlays (regions dead after edge1):
    ushort_t* h2  = h1;              // 32N bf16
    uint_t*   sp2 = sp1;             // N u32
    float*    ed2 = ed1;             // N f32

    zerob_kernel<<<8, 256, 0, stream>>>(bcnt, NB, pooled);
    gemm1_kernel<<<(N + 3) / 4, 256, 0, stream>>>(x, W1, a_s1, a_d1, h1, sp1, ed1, N);
    bhist_kernel<<<256, 256, 0, stream>>>(ei, E, N, bcnt, NB);
    bscan_kernel<<<1, 64, 0, stream>>>(bcnt, NB, boff, bcur);
    bscat_kernel<<<256, 256, 0, stream>>>(ei, E, N, bcur, pk, NB);
    edge1_gather<<<NB, 256, 0, stream>>>(bcnt, boff, pk, sp1, ed1, h1, o1, N);
    gemm2_kernel<<<(N + 7) / 8, 256, 0, stream>>>(o1, b1, W2, a_s2, a_d2, h2, sp2, ed2, N);
    edge2_gather<<<NB, 256, 0, stream>>>(bcnt, boff, pk, sp2, ed2, h2, b2, Wr, pooled, N);
    final_kernel<<<1, 64, 0, stream>>>(pooled, br, out);
}

// Round 8
// 580.297 us; speedup vs baseline: 1.0197x; 1.0197x over previous
//
#include <hip/hip_runtime.h>
#include <math.h>

#define NEG_SLOPE 0.2f
#define FIN 128
#define H1 8
#define F1 64   // HEADS1*HID
#define F2 32   // OUT2

#define SHIFT 6
#define BW 64          // dsts per bucket
#define CAP 4096       // max edges per bucket in LDS (avg ~2112, sigma ~46)
#define NBMAX 2048

typedef unsigned short ushort_t;
typedef unsigned int uint_t;

static __device__ __forceinline__ ushort_t f2bf(float f) {
    uint_t u = __float_as_uint(f);
    u = (u + 0x7FFFu + ((u >> 16) & 1u)) >> 16; // RNE
    return (ushort_t)u;
}
static __device__ __forceinline__ float bf2f(ushort_t h) {
    return __uint_as_float(((uint_t)h) << 16);
}
// pack {A=exp(e), B=exp(0.2e)} as bf16x2: A in low 16, B in high 16
static __device__ __forceinline__ uint_t packAB(float e) {
    return (uint_t)f2bf(__expf(e)) | ((uint_t)f2bf(__expf(NEG_SLOPE * e)) << 16);
}

// ---------------- Layer-1 GEMM: h1 = x @ W1 (bf16 out), fused exp-tables -----
// W1 staged in LDS once per block; 32 nodes/block (8 per wave, serial);
// x row is wave-uniform -> scalar (s_load) reads. No register tiling (R5 lesson).
__global__ void gemm1_kernel(const float* __restrict__ x, const float* __restrict__ W1,
                             const float* __restrict__ a_src, const float* __restrict__ a_dst,
                             ushort_t* __restrict__ h1, uint_t* __restrict__ sp,
                             float* __restrict__ ed, int N) {
    __shared__ float w1s[FIN * F1]; // 32 KB
    int tid = threadIdx.x;
    for (int i = tid; i < FIN * F1; i += 256) w1s[i] = W1[i];
    __syncthreads();
    int wv = tid >> 6, j = tid & 63;
    float as = a_src[j], ad = a_dst[j];
    int nbase = blockIdx.x * 32 + wv * 8;
    for (int t = 0; t < 8; ++t) {
        int n = nbase + t;
        if (n >= N) break;
        const float* xr = x + (size_t)n * FIN;  // wave-uniform base
        float acc = 0.f;
#pragma unroll 4
        for (int k = 0; k < FIN; ++k) acc = fmaf(xr[k], w1s[k * F1 + j], acc);
        h1[(size_t)n * F1 + j] = f2bf(acc);
        float vs = acc * as;
        float vd = acc * ad;
#pragma unroll
        for (int off = 4; off >= 1; off >>= 1) {
            vs += __shfl_down(vs, off, 8);
            vd += __shfl_down(vd, off, 8);
        }
        if ((j & 7) == 0) {
            sp[n * H1 + (j >> 3)] = packAB(vs);   // src-side exp table (bf16x2)
            ed[n * H1 + (j >> 3)] = vd;           // raw dst logit
        }
    }
}

// ---------------- bucket CSR build ------------------------------------------
__global__ void zerob_kernel(int* __restrict__ bcnt, int NB, float* __restrict__ pooled) {
    int t = blockIdx.x * blockDim.x + threadIdx.x;
    int stride = gridDim.x * blockDim.x;
    for (int i = t; i < NB; i += stride) bcnt[i] = 0;
    if (t == 0) pooled[0] = 0.f;
}

__global__ void bhist_kernel(const int* __restrict__ ei, int E, int N,
                             int* __restrict__ bcnt, int NB) {
    __shared__ int h[NBMAX];
    int tid = threadIdx.x;
    for (int i = tid; i < NB; i += 256) h[i] = 0;
    __syncthreads();
    int EN = E + N;
    int chunk = (EN + gridDim.x - 1) / gridDim.x;
    int e0 = blockIdx.x * chunk;
    int e1 = e0 + chunk; if (e1 > EN) e1 = EN;
    for (int t = e0 + tid; t < e1; t += 256) {
        int d = (t < E) ? ei[E + t] : (t - E);
        atomicAdd(&h[d >> SHIFT], 1);
    }
    __syncthreads();
    for (int i = tid; i < NB; i += 256)
        if (h[i]) atomicAdd(&bcnt[i], h[i]);
}

__global__ void bscan_kernel(const int* __restrict__ bcnt, int NB,
                             int* __restrict__ boff, int* __restrict__ bcur) {
    int lane = threadIdx.x; // 0..63
    int chunk = (NB + 63) >> 6;
    int lo = lane * chunk;
    int hi = lo + chunk; if (hi > NB) hi = NB;
    int sum = 0;
    for (int i = lo; i < hi; ++i) sum += bcnt[i];
    int e = sum;
#pragma unroll
    for (int o = 1; o < 64; o <<= 1) {
        int v = __shfl_up(e, o, 64);
        if (lane >= o) e += v;
    }
    e -= sum;
    int run = e;
    for (int i = lo; i < hi; ++i) {
        int c = bcnt[i];
        boff[i] = run;
        bcur[i] = run;
        run += c;
    }
}

__global__ void bscat_kernel(const int* __restrict__ ei, int E, int N,
                             int* __restrict__ bcur, uint_t* __restrict__ pk, int NB) {
    __shared__ int lh[NBMAX];
    __shared__ int lc[NBMAX];
    int tid = threadIdx.x;
    for (int i = tid; i < NB; i += 256) lh[i] = 0;
    __syncthreads();
    int EN = E + N;
    int chunk = (EN + gridDim.x - 1) / gridDim.x;
    int e0 = blockIdx.x * chunk;
    int e1 = e0 + chunk; if (e1 > EN) e1 = EN;
    for (int t = e0 + tid; t < e1; t += 256) {
        int d = (t < E) ? ei[E + t] : (t - E);
        atomicAdd(&lh[d >> SHIFT], 1);
    }
    __syncthreads();
    for (int i = tid; i < NB; i += 256) {
        int c = lh[i];
        lc[i] = c ? atomicAdd(&bcur[i], c) : 0;
    }
    __syncthreads();
    for (int t = e0 + tid; t < e1; t += 256) {
        int s, d;
        if (t < E) { s = ei[t]; d = ei[E + t]; } else { s = d = t - E; }
        int pos = atomicAdd(&lc[d >> SHIFT], 1);
        pk[pos] = ((uint_t)s << SHIFT) | (uint_t)(d & (BW - 1));
    }
}

// ---------------- Layer-1 edge pass: 8 edges/iter (2x pipelined), 4 ch/lane --
// one block per bucket; wave per dst (16 dsts/wave). Lane L: edge slot q=L>>4,
// channels c4=(L&15)*4 (one dwordx2 = 4 bf16), head (L&15)>>1.
__global__ void edge1_gather(const int* __restrict__ bcnt, const int* __restrict__ boff,
                             const uint_t* __restrict__ pk,
                             const uint_t* __restrict__ sp, const float* __restrict__ ed,
                             const ushort_t* __restrict__ h1, float* __restrict__ o1, int N) {
    int b = blockIdx.x;
    int d0 = b << SHIFT;
    int cnt = bcnt[b];
    int gbase = boff[b];
    int tid = threadIdx.x;
    int wv = tid >> 6;
    int L = tid & 63;
    int q = L >> 4;           // edge slot 0..3
    int c4 = (L & 15) << 2;   // channel base
    int hL = (L & 15) >> 1;   // head of channels c4..c4+3
    __shared__ int ldeg[BW];
    __shared__ int loff[BW];
    __shared__ int lcur[BW];
    __shared__ int lsrc[CAP];
    if (cnt <= CAP) {
        if (tid < BW) ldeg[tid] = 0;
        __syncthreads();
        for (int k = tid; k < cnt; k += 256) atomicAdd(&ldeg[pk[gbase + k] & (BW - 1)], 1);
        __syncthreads();
        if (tid < 64) {
            int v = ldeg[tid];
            int e = v;
#pragma unroll
            for (int o = 1; o < 64; o <<= 1) {
                int u = __shfl_up(e, o, 64);
                if (tid >= o) e += u;
            }
            e -= v;
            loff[tid] = e;
            lcur[tid] = e;
        }
        __syncthreads();
        for (int k = tid; k < cnt; k += 256) {
            uint_t v = pk[gbase + k];
            int pos = atomicAdd(&lcur[v & (BW - 1)], 1);
            lsrc[pos] = (int)(v >> SHIFT);
        }
        __syncthreads();
        for (int ld = wv * 16; ld < wv * 16 + 16; ++ld) {
            int d = d0 + ld;
            if (d >= N) break;
            int st = loff[ld], en = st + ldeg[ld];
            float edv = ed[d * H1 + hL];
            float Ad = __expf(edv), Bd = __expf(NEG_SLOPE * edv);
            float ax = 0.f, ay = 0.f, az = 0.f, aw = 0.f, wsum = 0.f;
            for (int k = st; k < en; k += 8) {
                // issue both groups' loads before any use (MLP = 8/lane-group)
                int i0 = k + q, i1 = k + 4 + q;
                bool ok0 = i0 < en, ok1 = i1 < en;
                int s0 = lsrc[ok0 ? i0 : st];   // st valid: self-loop => en>st
                int s1 = lsrc[ok1 ? i1 : st];
                uint_t u0 = sp[(uint_t)s0 * H1 + hL];
                uint_t u1 = sp[(uint_t)s1 * H1 + hL];
                uint2 hv0 = *(const uint2*)(h1 + ((uint_t)s0 << 6) + c4);
                uint2 hv1 = *(const uint2*)(h1 + ((uint_t)s1 << 6) + c4);
                float w0 = ok0 ? fmaxf(__uint_as_float(u0 << 16) * Ad,
                                       __uint_as_float(u0 & 0xffff0000u) * Bd) : 0.f;
                float w1 = ok1 ? fmaxf(__uint_as_float(u1 << 16) * Ad,
                                       __uint_as_float(u1 & 0xffff0000u) * Bd) : 0.f;
                ax = fmaf(w0, __uint_as_float(hv0.x << 16), ax);
                ay = fmaf(w0, __uint_as_float(hv0.x & 0xffff0000u), ay);
                az = fmaf(w0, __uint_as_float(hv0.y << 16), az);
                aw = fmaf(w0, __uint_as_float(hv0.y & 0xffff0000u), aw);
                ax = fmaf(w1, __uint_as_float(hv1.x << 16), ax);
                ay = fmaf(w1, __uint_as_float(hv1.x & 0xffff0000u), ay);
                az = fmaf(w1, __uint_as_float(hv1.y << 16), az);
                aw = fmaf(w1, __uint_as_float(hv1.y & 0xffff0000u), aw);
                wsum += w0 + w1;
            }
            // fold the 4 edge slots (lanes differing in bits 4..5)
            ax += __shfl_xor(ax, 16, 64); ax += __shfl_xor(ax, 32, 64);
            ay += __shfl_xor(ay, 16, 64); ay += __shfl_xor(ay, 32, 64);
            az += __shfl_xor(az, 16, 64); az += __shfl_xor(az, 32, 64);
            aw += __shfl_xor(aw, 16, 64); aw += __shfl_xor(aw, 32, 64);
            wsum += __shfl_xor(wsum, 16, 64); wsum += __shfl_xor(wsum, 32, 64);
            if (q == 0) {
                float inv = 1.f / wsum;
                float4 r; r.x = ax * inv; r.y = ay * inv; r.z = az * inv; r.w = aw * inv;
                *(float4*)(o1 + (size_t)d * F1 + c4) = r;
            }
        }
    } else {
        // statistically unreachable fallback: scan whole bucket per dst
        for (int ld = wv * 16; ld < wv * 16 + 16; ++ld) {
            int d = d0 + ld;
            if (d >= N) break;
            float edv = ed[d * H1 + hL];
            float Ad = __expf(edv), Bd = __expf(NEG_SLOPE * edv);
            float ax = 0.f, ay = 0.f, az = 0.f, aw = 0.f, wsum = 0.f;
            for (int k0 = 0; k0 < cnt; k0 += 4) {
                int idx = k0 + q;
                bool ok = idx < cnt;
                uint_t v = pk[gbase + (ok ? idx : 0)];
                int s = (int)(v >> SHIFT);
                bool m = ok && ((int)(v & (BW - 1)) == ld);
                uint_t u = sp[(uint_t)s * H1 + hL];
                float w = m ? fmaxf(__uint_as_float(u << 16) * Ad,
                                    __uint_as_float(u & 0xffff0000u) * Bd) : 0.f;
                uint2 hv = *(const uint2*)(h1 + ((uint_t)s << 6) + c4);
                ax = fmaf(w, __uint_as_float(hv.x << 16), ax);
                ay = fmaf(w, __uint_as_float(hv.x & 0xffff0000u), ay);
                az = fmaf(w, __uint_as_float(hv.y << 16), az);
                aw = fmaf(w, __uint_as_float(hv.y & 0xffff0000u), aw);
                wsum += w;
            }
            ax += __shfl_xor(ax, 16, 64); ax += __shfl_xor(ax, 32, 64);
            ay += __shfl_xor(ay, 16, 64); ay += __shfl_xor(ay, 32, 64);
            az += __shfl_xor(az, 16, 64); az += __shfl_xor(az, 32, 64);
            aw += __shfl_xor(aw, 16, 64); aw += __shfl_xor(aw, 32, 64);
            wsum += __shfl_xor(wsum, 16, 64); wsum += __shfl_xor(wsum, 32, 64);
            if (q == 0) {
                float inv = 1.f / wsum;
                float4 r; r.x = ax * inv; r.y = ay * inv; r.z = az * inv; r.w = aw * inv;
                *(float4*)(o1 + (size_t)d * F1 + c4) = r;
            }
        }
    }
}

// ---------------- Layer-2 GEMM: a1 = elu(o1 + b1); h2 = a1 @ W2 (bf16) -------
__global__ void gemm2_kernel(const float* __restrict__ o1, const float* __restrict__ b1,
                             const float* __restrict__ W2,
                             const float* __restrict__ a_src2, const float* __restrict__ a_dst2,
                             ushort_t* __restrict__ h2, uint_t* __restrict__ sp2,
                             float* __restrict__ ed2, int N) {
    int half = threadIdx.x >> 5;
    int n = blockIdx.x * 8 + half;
    int j = threadIdx.x & 31;
    __shared__ float a1s[8][F1];
    if (n < N) {
#pragma unroll
        for (int r = 0; r < 2; ++r) {
            int k = r * 32 + j;
            float v = o1[(size_t)n * F1 + k] + b1[k];
            a1s[half][k] = v > 0.f ? v : expm1f(v); // ELU
        }
    }
    __syncthreads();
    if (n >= N) return;
    float acc = 0.f;
#pragma unroll
    for (int k = 0; k < F1; ++k) acc = fmaf(a1s[half][k], W2[k * F2 + j], acc);
    h2[(size_t)n * F2 + j] = f2bf(acc);
    float vs = acc * a_src2[j];
    float vd = acc * a_dst2[j];
#pragma unroll
    for (int off = 16; off >= 1; off >>= 1) {
        vs += __shfl_down(vs, off, 32);
        vd += __shfl_down(vd, off, 32);
    }
    if (j == 0) {
        sp2[n] = packAB(vs);
        ed2[n] = vd;
    }
}

// ---------------- Layer-2 edge pass (R6 proven version): exp-free gather -----
// one block per bucket; half-wave per dst (8 dsts per half-wave)
__global__ void edge2_gather(const int* __restrict__ bcnt, const int* __restrict__ boff,
                             const uint_t* __restrict__ pk,
                             const uint_t* __restrict__ sp2, const float* __restrict__ ed2,
                             const ushort_t* __restrict__ h2,
                             const float* __restrict__ b2, const float* __restrict__ Wr,
                             float* __restrict__ pooled, int N) {
    int b = blockIdx.x;
    int d0 = b << SHIFT;
    int cnt = bcnt[b];
    int gbase = boff[b];
    int tid = threadIdx.x;
    int hw = tid >> 5;  // 0..7
    int j = tid & 31;
    __shared__ int ldeg[BW];
    __shared__ int loff[BW];
    __shared__ int lcur[BW];
    __shared__ int lsrc[CAP];
    float wr = Wr[j];
    float b2w = b2[j] * wr;
    float part = 0.f;
    if (cnt <= CAP) {
        if (tid < BW) ldeg[tid] = 0;
        __syncthreads();
        for (int k = tid; k < cnt; k += 256) atomicAdd(&ldeg[pk[gbase + k] & (BW - 1)], 1);
        __syncthreads();
        if (tid < 64) {
            int v = ldeg[tid];
            int e = v;
#pragma unroll
            for (int o = 1; o < 64; o <<= 1) {
                int u = __shfl_up(e, o, 64);
                if (tid >= o) e += u;
            }
            e -= v;
            loff[tid] = e;
            lcur[tid] = e;
        }
        __syncthreads();
        for (int k = tid; k < cnt; k += 256) {
            uint_t v = pk[gbase + k];
            int pos = atomicAdd(&lcur[v & (BW - 1)], 1);
            lsrc[pos] = (int)(v >> SHIFT);
        }
        __syncthreads();
        for (int ld = hw * 8; ld < hw * 8 + 8; ++ld) {
            int d = d0 + ld;
            if (d >= N) break;
            int st = loff[ld], dg = ldeg[ld];
            float edv = ed2[d];
            float Ad = __expf(edv), Bd = __expf(NEG_SLOPE * edv);
            float acc = 0.f, wsum = 0.f;
#pragma unroll 4
            for (int k = st; k < st + dg; ++k) {
                int s = lsrc[k];
                uint_t u = sp2[s];
                float w = fmaxf(__uint_as_float(u << 16) * Ad,
                                __uint_as_float(u & 0xffff0000u) * Bd);
                acc = fmaf(w, bf2f(h2[(size_t)s * F2 + j]), acc);
                wsum += w;
            }
            part = fmaf(acc / wsum, wr, part + b2w);
        }
    } else {
        for (int ld = hw * 8; ld < hw * 8 + 8; ++ld) {
            int d = d0 + ld;
            if (d >= N) break;
            float edv = ed2[d];
            float Ad = __expf(edv), Bd = __expf(NEG_SLOPE * edv);
            float acc = 0.f, wsum = 0.f;
            for (int k = 0; k < cnt; ++k) {
                uint_t v = pk[gbase + k];
                if ((int)(v & (BW - 1)) != ld) continue;
                int s = (int)(v >> SHIFT);
                uint_t u = sp2[s];
                float w = fmaxf(__uint_as_float(u << 16) * Ad,
                                __uint_as_float(u & 0xffff0000u) * Bd);
                acc = fmaf(w, bf2f(h2[(size_t)s * F2 + j]), acc);
                wsum += w;
            }
            part = fmaf(acc / wsum, wr, part + b2w);
        }
    }
    // block reduction -> one atomic
#pragma unroll
    for (int o = 32; o >= 1; o >>= 1) part += __shfl_down(part, o, 64);
    __shared__ float ls[4];
    int wave = tid >> 6;
    if ((tid & 63) == 0) ls[wave] = part;
    __syncthreads();
    if (tid == 0) atomicAdd(pooled, ls[0] + ls[1] + ls[2] + ls[3]);
}

__global__ void final_kernel(const float* __restrict__ pooled, const float* __restrict__ br,
                             float* __restrict__ out) {
    if (threadIdx.x == 0 && blockIdx.x == 0) out[0] = pooled[0] + br[0];
}

extern "C" void kernel_launch(void* const* d_in, const int* in_sizes, int n_in,
                              void* d_out, int out_size, void* d_ws, size_t ws_size,
                              hipStream_t stream) {
    const float* x    = (const float*)d_in[0];
    const int*   ei   = (const int*)d_in[1];
    const float* W1   = (const float*)d_in[2];
    const float* a_s1 = (const float*)d_in[3];
    const float* a_d1 = (const float*)d_in[4];
    const float* b1   = (const float*)d_in[5];
    const float* W2   = (const float*)d_in[6];
    const float* a_s2 = (const float*)d_in[7];
    const float* a_d2 = (const float*)d_in[8];
    const float* b2   = (const float*)d_in[9];
    const float* Wr   = (const float*)d_in[10];
    const float* br   = (const float*)d_in[11];
    float* out = (float*)d_out;

    int N = in_sizes[0] / FIN;
    int E = in_sizes[1] / 2;
    size_t n = (size_t)N;
    int NB = (N + BW - 1) >> SHIFT;

    // workspace layout (bytes), total ~= 58 MB for N=100k, E=3.2M
    char* ws = (char*)d_ws;
    float*    o1   = (float*)ws;                          // 64N f32
    uint_t*   sp1  = (uint_t*)(ws + n * 256);             // 8N u32 (bf16x2 exp table)
    float*    ed1  = (float*)(ws + n * 288);              // 8N f32
    ushort_t* h1   = (ushort_t*)(ws + n * 320);           // 64N bf16
    uint_t*   pk   = (uint_t*)(ws + n * 448);             // (E+N) uint
    char*     tail = ws + n * 448 + (size_t)(E + N) * 4;
    int*      bcnt = (int*)tail;                          // NBMAX int
    int*      boff = (int*)(tail + NBMAX * 4);            // NBMAX int
    int*      bcur = (int*)(tail + NBMAX * 8);            // NBMAX int
    float*  pooled = (float*)(tail + NBMAX * 12);         // 1 f32
    // layer-2 overlays (regions dead after edge1):
    ushort_t* h2  = h1;              // 32N bf16
    uint_t*   sp2 = sp1;             // N u32
    float*    ed2 = ed1;             // N f32

    zerob_kernel<<<8, 256, 0, stream>>>(bcnt, NB, pooled);
    gemm1_kernel<<<(N + 31) / 32, 256, 0, stream>>>(x, W1, a_s1, a_d1, h1, sp1, ed1, N);
    bhist_kernel<<<256, 256, 0, stream>>>(ei, E, N, bcnt, NB);
    bscan_kernel<<<1, 64, 0, stream>>>(bcnt, NB, boff, bcur);
    bscat_kernel<<<256, 256, 0, stream>>>(ei, E, N, bcur, pk, NB);
    edge1_gather<<<NB, 256, 0, stream>>>(bcnt, boff, pk, sp1, ed1, h1, o1, N);
    gemm2_kernel<<<(N + 7) / 8, 256, 0, stream>>>(o1, b1, W2, a_s2, a_d2, h2, sp2, ed2, N);
    edge2_gather<<<NB, 256, 0, stream>>>(bcnt, boff, pk, sp2, ed2, h2, b2, Wr, pooled, N);
    final_kernel<<<1, 64, 0, stream>>>(pooled, br, out);
}

// Round 9
// 454.304 us; speedup vs baseline: 1.3025x; 1.2773x over previous
//
#include <hip/hip_runtime.h>
#include <math.h>

#define NEG_SLOPE 0.2f
#define FIN 128
#define H1 8
#define F1 64   // HEADS1*HID
#define F2 32   // OUT2

#define SHIFT 6
#define BW 64          // dsts per bucket
#define CAP 4096       // max edges per bucket in LDS (avg ~2112, sigma ~46)
#define NBMAX 2048

typedef unsigned short ushort_t;
typedef unsigned int uint_t;

static __device__ __forceinline__ ushort_t f2bf(float f) {
    uint_t u = __float_as_uint(f);
    u = (u + 0x7FFFu + ((u >> 16) & 1u)) >> 16; // RNE
    return (ushort_t)u;
}
static __device__ __forceinline__ float bf2f(ushort_t h) {
    return __uint_as_float(((uint_t)h) << 16);
}
// pack {A=exp(e), B=exp(0.2e)} as bf16x2: A in low 16, B in high 16
static __device__ __forceinline__ uint_t packAB(float e) {
    return (uint_t)f2bf(__expf(e)) | ((uint_t)f2bf(__expf(NEG_SLOPE * e)) << 16);
}

// ---------------- Layer-1 GEMM: h1 = x @ W1 (bf16 out), fused exp-tables -----
// 16 nodes/block staged in LDS (coalesced); wave = 4 nodes, 4 accumulators;
// W1 read coalesced from global (L1/L2-hot), x via wave-uniform ds_read_b128.
// #pragma unroll 2 caps register pressure (R5 spill lesson).
__global__ void gemm1_kernel(const float* __restrict__ x, const float* __restrict__ W1,
                             const float* __restrict__ a_src, const float* __restrict__ a_dst,
                             ushort_t* __restrict__ h1, uint_t* __restrict__ sp,
                             float* __restrict__ ed, int N) {
    __shared__ float xs[16][FIN]; // 8 KB
    int tid = threadIdx.x;
    int n0 = blockIdx.x * 16;
    for (int i = tid; i < 16 * FIN; i += 256) {
        int nn = n0 + (i >> 7);
        xs[i >> 7][i & 127] = (nn < N) ? x[(size_t)nn * FIN + (i & 127)] : 0.f;
    }
    __syncthreads();
    int wv = tid >> 6, j = tid & 63;
    int nb = wv << 2; // this wave's 4 local nodes
    float a0 = 0.f, a1 = 0.f, a2 = 0.f, a3 = 0.f;
#pragma unroll 2
    for (int k = 0; k < FIN; k += 4) {
        float w0 = W1[(k + 0) * F1 + j];
        float w1 = W1[(k + 1) * F1 + j];
        float w2 = W1[(k + 2) * F1 + j];
        float w3 = W1[(k + 3) * F1 + j];
        float4 x0 = *(const float4*)&xs[nb + 0][k];
        float4 x1 = *(const float4*)&xs[nb + 1][k];
        float4 x2 = *(const float4*)&xs[nb + 2][k];
        float4 x3 = *(const float4*)&xs[nb + 3][k];
        a0 = fmaf(x0.x, w0, fmaf(x0.y, w1, fmaf(x0.z, w2, fmaf(x0.w, w3, a0))));
        a1 = fmaf(x1.x, w0, fmaf(x1.y, w1, fmaf(x1.z, w2, fmaf(x1.w, w3, a1))));
        a2 = fmaf(x2.x, w0, fmaf(x2.y, w1, fmaf(x2.z, w2, fmaf(x2.w, w3, a2))));
        a3 = fmaf(x3.x, w0, fmaf(x3.y, w1, fmaf(x3.z, w2, fmaf(x3.w, w3, a3))));
    }
    float as = a_src[j], ad = a_dst[j];
    float av[4] = {a0, a1, a2, a3};
#pragma unroll
    for (int t = 0; t < 4; ++t) {
        int n = n0 + nb + t;
        if (n >= N) break;
        h1[(size_t)n * F1 + j] = f2bf(av[t]);
        float vs = av[t] * as;
        float vd = av[t] * ad;
#pragma unroll
        for (int off = 4; off >= 1; off >>= 1) {
            vs += __shfl_down(vs, off, 8);
            vd += __shfl_down(vd, off, 8);
        }
        if ((j & 7) == 0) {
            sp[n * H1 + (j >> 3)] = packAB(vs);   // src-side exp table (bf16x2)
            ed[n * H1 + (j >> 3)] = vd;           // raw dst logit
        }
    }
}

// ---------------- bucket CSR build ------------------------------------------
__global__ void zerob_kernel(int* __restrict__ bcnt, int NB, float* __restrict__ pooled) {
    int t = blockIdx.x * blockDim.x + threadIdx.x;
    int stride = gridDim.x * blockDim.x;
    for (int i = t; i < NB; i += stride) bcnt[i] = 0;
    if (t == 0) pooled[0] = 0.f;
}

__global__ void bhist_kernel(const int* __restrict__ ei, int E, int N,
                             int* __restrict__ bcnt, int NB) {
    __shared__ int h[NBMAX];
    int tid = threadIdx.x;
    for (int i = tid; i < NB; i += 256) h[i] = 0;
    __syncthreads();
    int EN = E + N;
    int chunk = (EN + gridDim.x - 1) / gridDim.x;
    int e0 = blockIdx.x * chunk;
    int e1 = e0 + chunk; if (e1 > EN) e1 = EN;
    for (int t = e0 + tid; t < e1; t += 256) {
        int d = (t < E) ? ei[E + t] : (t - E);
        atomicAdd(&h[d >> SHIFT], 1);
    }
    __syncthreads();
    for (int i = tid; i < NB; i += 256)
        if (h[i]) atomicAdd(&bcnt[i], h[i]);
}

__global__ void bscan_kernel(const int* __restrict__ bcnt, int NB,
                             int* __restrict__ boff, int* __restrict__ bcur) {
    int lane = threadIdx.x; // 0..63
    int chunk = (NB + 63) >> 6;
    int lo = lane * chunk;
    int hi = lo + chunk; if (hi > NB) hi = NB;
    int sum = 0;
    for (int i = lo; i < hi; ++i) sum += bcnt[i];
    int e = sum;
#pragma unroll
    for (int o = 1; o < 64; o <<= 1) {
        int v = __shfl_up(e, o, 64);
        if (lane >= o) e += v;
    }
    e -= sum;
    int run = e;
    for (int i = lo; i < hi; ++i) {
        int c = bcnt[i];
        boff[i] = run;
        bcur[i] = run;
        run += c;
    }
}

__global__ void bscat_kernel(const int* __restrict__ ei, int E, int N,
                             int* __restrict__ bcur, uint_t* __restrict__ pk, int NB) {
    __shared__ int lh[NBMAX];
    __shared__ int lc[NBMAX];
    int tid = threadIdx.x;
    for (int i = tid; i < NB; i += 256) lh[i] = 0;
    __syncthreads();
    int EN = E + N;
    int chunk = (EN + gridDim.x - 1) / gridDim.x;
    int e0 = blockIdx.x * chunk;
    int e1 = e0 + chunk; if (e1 > EN) e1 = EN;
    for (int t = e0 + tid; t < e1; t += 256) {
        int d = (t < E) ? ei[E + t] : (t - E);
        atomicAdd(&lh[d >> SHIFT], 1);
    }
    __syncthreads();
    for (int i = tid; i < NB; i += 256) {
        int c = lh[i];
        lc[i] = c ? atomicAdd(&bcur[i], c) : 0;
    }
    __syncthreads();
    for (int t = e0 + tid; t < e1; t += 256) {
        int s, d;
        if (t < E) { s = ei[t]; d = ei[E + t]; } else { s = d = t - E; }
        int pos = atomicAdd(&lc[d >> SHIFT], 1);
        pk[pos] = ((uint_t)s << SHIFT) | (uint_t)(d & (BW - 1));
    }
}

// ---------------- Layer-1 edge pass: 8 edges/iter (2x pipelined), 4 ch/lane --
// one block per bucket; wave per dst (16 dsts/wave). Lane L: edge slot q=L>>4,
// channels c4=(L&15)*4 (one dwordx2 = 4 bf16), head (L&15)>>1.
__global__ void edge1_gather(const int* __restrict__ bcnt, const int* __restrict__ boff,
                             const uint_t* __restrict__ pk,
                             const uint_t* __restrict__ sp, const float* __restrict__ ed,
                             const ushort_t* __restrict__ h1, float* __restrict__ o1, int N) {
    int b = blockIdx.x;
    int d0 = b << SHIFT;
    int cnt = bcnt[b];
    int gbase = boff[b];
    int tid = threadIdx.x;
    int wv = tid >> 6;
    int L = tid & 63;
    int q = L >> 4;           // edge slot 0..3
    int c4 = (L & 15) << 2;   // channel base
    int hL = (L & 15) >> 1;   // head of channels c4..c4+3
    __shared__ int ldeg[BW];
    __shared__ int loff[BW];
    __shared__ int lcur[BW];
    __shared__ int lsrc[CAP];
    if (cnt <= CAP) {
        if (tid < BW) ldeg[tid] = 0;
        __syncthreads();
        for (int k = tid; k < cnt; k += 256) atomicAdd(&ldeg[pk[gbase + k] & (BW - 1)], 1);
        __syncthreads();
        if (tid < 64) {
            int v = ldeg[tid];
            int e = v;
#pragma unroll
            for (int o = 1; o < 64; o <<= 1) {
                int u = __shfl_up(e, o, 64);
                if (tid >= o) e += u;
            }
            e -= v;
            loff[tid] = e;
            lcur[tid] = e;
        }
        __syncthreads();
        for (int k = tid; k < cnt; k += 256) {
            uint_t v = pk[gbase + k];
            int pos = atomicAdd(&lcur[v & (BW - 1)], 1);
            lsrc[pos] = (int)(v >> SHIFT);
        }
        __syncthreads();
        for (int ld = wv * 16; ld < wv * 16 + 16; ++ld) {
            int d = d0 + ld;
            if (d >= N) break;
            int st = loff[ld], en = st + ldeg[ld];
            float edv = ed[d * H1 + hL];
            float Ad = __expf(edv), Bd = __expf(NEG_SLOPE * edv);
            float ax = 0.f, ay = 0.f, az = 0.f, aw = 0.f, wsum = 0.f;
            for (int k = st; k < en; k += 8) {
                // issue both groups' loads before any use (MLP = 8/lane-group)
                int i0 = k + q, i1 = k + 4 + q;
                bool ok0 = i0 < en, ok1 = i1 < en;
                int s0 = lsrc[ok0 ? i0 : st];   // st valid: self-loop => en>st
                int s1 = lsrc[ok1 ? i1 : st];
                uint_t u0 = sp[(uint_t)s0 * H1 + hL];
                uint_t u1 = sp[(uint_t)s1 * H1 + hL];
                uint2 hv0 = *(const uint2*)(h1 + ((uint_t)s0 << 6) + c4);
                uint2 hv1 = *(const uint2*)(h1 + ((uint_t)s1 << 6) + c4);
                float w0 = ok0 ? fmaxf(__uint_as_float(u0 << 16) * Ad,
                                       __uint_as_float(u0 & 0xffff0000u) * Bd) : 0.f;
                float w1 = ok1 ? fmaxf(__uint_as_float(u1 << 16) * Ad,
                                       __uint_as_float(u1 & 0xffff0000u) * Bd) : 0.f;
                ax = fmaf(w0, __uint_as_float(hv0.x << 16), ax);
                ay = fmaf(w0, __uint_as_float(hv0.x & 0xffff0000u), ay);
                az = fmaf(w0, __uint_as_float(hv0.y << 16), az);
                aw = fmaf(w0, __uint_as_float(hv0.y & 0xffff0000u), aw);
                ax = fmaf(w1, __uint_as_float(hv1.x << 16), ax);
                ay = fmaf(w1, __uint_as_float(hv1.x & 0xffff0000u), ay);
                az = fmaf(w1, __uint_as_float(hv1.y << 16), az);
                aw = fmaf(w1, __uint_as_float(hv1.y & 0xffff0000u), aw);
                wsum += w0 + w1;
            }
            // fold the 4 edge slots (lanes differing in bits 4..5)
            ax += __shfl_xor(ax, 16, 64); ax += __shfl_xor(ax, 32, 64);
            ay += __shfl_xor(ay, 16, 64); ay += __shfl_xor(ay, 32, 64);
            az += __shfl_xor(az, 16, 64); az += __shfl_xor(az, 32, 64);
            aw += __shfl_xor(aw, 16, 64); aw += __shfl_xor(aw, 32, 64);
            wsum += __shfl_xor(wsum, 16, 64); wsum += __shfl_xor(wsum, 32, 64);
            if (q == 0) {
                float inv = 1.f / wsum;
                float4 r; r.x = ax * inv; r.y = ay * inv; r.z = az * inv; r.w = aw * inv;
                *(float4*)(o1 + (size_t)d * F1 + c4) = r;
            }
        }
    } else {
        // statistically unreachable fallback: scan whole bucket per dst
        for (int ld = wv * 16; ld < wv * 16 + 16; ++ld) {
            int d = d0 + ld;
            if (d >= N) break;
            float edv = ed[d * H1 + hL];
            float Ad = __expf(edv), Bd = __expf(NEG_SLOPE * edv);
            float ax = 0.f, ay = 0.f, az = 0.f, aw = 0.f, wsum = 0.f;
            for (int k0 = 0; k0 < cnt; k0 += 4) {
                int idx = k0 + q;
                bool ok = idx < cnt;
                uint_t v = pk[gbase + (ok ? idx : 0)];
                int s = (int)(v >> SHIFT);
                bool m = ok && ((int)(v & (BW - 1)) == ld);
                uint_t u = sp[(uint_t)s * H1 + hL];
                float w = m ? fmaxf(__uint_as_float(u << 16) * Ad,
                                    __uint_as_float(u & 0xffff0000u) * Bd) : 0.f;
                uint2 hv = *(const uint2*)(h1 + ((uint_t)s << 6) + c4);
                ax = fmaf(w, __uint_as_float(hv.x << 16), ax);
                ay = fmaf(w, __uint_as_float(hv.x & 0xffff0000u), ay);
                az = fmaf(w, __uint_as_float(hv.y << 16), az);
                aw = fmaf(w, __uint_as_float(hv.y & 0xffff0000u), aw);
                wsum += w;
            }
            ax += __shfl_xor(ax, 16, 64); ax += __shfl_xor(ax, 32, 64);
            ay += __shfl_xor(ay, 16, 64); ay += __shfl_xor(ay, 32, 64);
            az += __shfl_xor(az, 16, 64); az += __shfl_xor(az, 32, 64);
            aw += __shfl_xor(aw, 16, 64); aw += __shfl_xor(aw, 32, 64);
            wsum += __shfl_xor(wsum, 16, 64); wsum += __shfl_xor(wsum, 32, 64);
            if (q == 0) {
                float inv = 1.f / wsum;
                float4 r; r.x = ax * inv; r.y = ay * inv; r.z = az * inv; r.w = aw * inv;
                *(float4*)(o1 + (size_t)d * F1 + c4) = r;
            }
        }
    }
}

// ---------------- Layer-2 GEMM: a1 = elu(o1 + b1); h2 = a1 @ W2 (bf16) -------
__global__ void gemm2_kernel(const float* __restrict__ o1, const float* __restrict__ b1,
                             const float* __restrict__ W2,
                             const float* __restrict__ a_src2, const float* __restrict__ a_dst2,
                             ushort_t* __restrict__ h2, uint_t* __restrict__ sp2,
                             float* __restrict__ ed2, int N) {
    int half = threadIdx.x >> 5;
    int n = blockIdx.x * 8 + half;
    int j = threadIdx.x & 31;
    __shared__ float a1s[8][F1];
    if (n < N) {
#pragma unroll
        for (int r = 0; r < 2; ++r) {
            int k = r * 32 + j;
            float v = o1[(size_t)n * F1 + k] + b1[k];
            a1s[half][k] = v > 0.f ? v : expm1f(v); // ELU
        }
    }
    __syncthreads();
    if (n >= N) return;
    float acc = 0.f;
#pragma unroll
    for (int k = 0; k < F1; ++k) acc = fmaf(a1s[half][k], W2[k * F2 + j], acc);
    h2[(size_t)n * F2 + j] = f2bf(acc);
    float vs = acc * a_src2[j];
    float vd = acc * a_dst2[j];
#pragma unroll
    for (int off = 16; off >= 1; off >>= 1) {
        vs += __shfl_down(vs, off, 32);
        vd += __shfl_down(vd, off, 32);
    }
    if (j == 0) {
        sp2[n] = packAB(vs);
        ed2[n] = vd;
    }
}

// ---------------- Layer-2 edge pass (R6 proven version): exp-free gather -----
// one block per bucket; half-wave per dst (8 dsts per half-wave)
__global__ void edge2_gather(const int* __restrict__ bcnt, const int* __restrict__ boff,
                             const uint_t* __restrict__ pk,
                             const uint_t* __restrict__ sp2, const float* __restrict__ ed2,
                             const ushort_t* __restrict__ h2,
                             const float* __restrict__ b2, const float* __restrict__ Wr,
                             float* __restrict__ pooled, int N) {
    int b = blockIdx.x;
    int d0 = b << SHIFT;
    int cnt = bcnt[b];
    int gbase = boff[b];
    int tid = threadIdx.x;
    int hw = tid >> 5;  // 0..7
    int j = tid & 31;
    __shared__ int ldeg[BW];
    __shared__ int loff[BW];
    __shared__ int lcur[BW];
    __shared__ int lsrc[CAP];
    float wr = Wr[j];
    float b2w = b2[j] * wr;
    float part = 0.f;
    if (cnt <= CAP) {
        if (tid < BW) ldeg[tid] = 0;
        __syncthreads();
        for (int k = tid; k < cnt; k += 256) atomicAdd(&ldeg[pk[gbase + k] & (BW - 1)], 1);
        __syncthreads();
        if (tid < 64) {
            int v = ldeg[tid];
            int e = v;
#pragma unroll
            for (int o = 1; o < 64; o <<= 1) {
                int u = __shfl_up(e, o, 64);
                if (tid >= o) e += u;
            }
            e -= v;
            loff[tid] = e;
            lcur[tid] = e;
        }
        __syncthreads();
        for (int k = tid; k < cnt; k += 256) {
            uint_t v = pk[gbase + k];
            int pos = atomicAdd(&lcur[v & (BW - 1)], 1);
            lsrc[pos] = (int)(v >> SHIFT);
        }
        __syncthreads();
        for (int ld = hw * 8; ld < hw * 8 + 8; ++ld) {
            int d = d0 + ld;
            if (d >= N) break;
            int st = loff[ld], dg = ldeg[ld];
            float edv = ed2[d];
            float Ad = __expf(edv), Bd = __expf(NEG_SLOPE * edv);
            float acc = 0.f, wsum = 0.f;
#pragma unroll 4
            for (int k = st; k < st + dg; ++k) {
                int s = lsrc[k];
                uint_t u = sp2[s];
                float w = fmaxf(__uint_as_float(u << 16) * Ad,
                                __uint_as_float(u & 0xffff0000u) * Bd);
                acc = fmaf(w, bf2f(h2[(size_t)s * F2 + j]), acc);
                wsum += w;
            }
            part = fmaf(acc / wsum, wr, part + b2w);
        }
    } else {
        for (int ld = hw * 8; ld < hw * 8 + 8; ++ld) {
            int d = d0 + ld;
            if (d >= N) break;
            float edv = ed2[d];
            float Ad = __expf(edv), Bd = __expf(NEG_SLOPE * edv);
            float acc = 0.f, wsum = 0.f;
            for (int k = 0; k < cnt; ++k) {
                uint_t v = pk[gbase + k];
                if ((int)(v & (BW - 1)) != ld) continue;
                int s = (int)(v >> SHIFT);
                uint_t u = sp2[s];
                float w = fmaxf(__uint_as_float(u << 16) * Ad,
                                __uint_as_float(u & 0xffff0000u) * Bd);
                acc = fmaf(w, bf2f(h2[(size_t)s * F2 + j]), acc);
                wsum += w;
            }
            part = fmaf(acc / wsum, wr, part + b2w);
        }
    }
    // block reduction -> one atomic
#pragma unroll
    for (int o = 32; o >= 1; o >>= 1) part += __shfl_down(part, o, 64);
    __shared__ float ls[4];
    int wave = tid >> 6;
    if ((tid & 63) == 0) ls[wave] = part;
    __syncthreads();
    if (tid == 0) atomicAdd(pooled, ls[0] + ls[1] + ls[2] + ls[3]);
}

__global__ void final_kernel(const float* __restrict__ pooled, const float* __restrict__ br,
                             float* __restrict__ out) {
    if (threadIdx.x == 0 && blockIdx.x == 0) out[0] = pooled[0] + br[0];
}

extern "C" void kernel_launch(void* const* d_in, const int* in_sizes, int n_in,
                              void* d_out, int out_size, void* d_ws, size_t ws_size,
                              hipStream_t stream) {
    const float* x    = (const float*)d_in[0];
    const int*   ei   = (const int*)d_in[1];
    const float* W1   = (const float*)d_in[2];
    const float* a_s1 = (const float*)d_in[3];
    const float* a_d1 = (const float*)d_in[4];
    const float* b1   = (const float*)d_in[5];
    const float* W2   = (const float*)d_in[6];
    const float* a_s2 = (const float*)d_in[7];
    const float* a_d2 = (const float*)d_in[8];
    const float* b2   = (const float*)d_in[9];
    const float* Wr   = (const float*)d_in[10];
    const float* br   = (const float*)d_in[11];
    float* out = (float*)d_out;

    int N = in_sizes[0] / FIN;
    int E = in_sizes[1] / 2;
    size_t n = (size_t)N;
    int NB = (N + BW - 1) >> SHIFT;

    // workspace layout (bytes), total ~= 58 MB for N=100k, E=3.2M
    char* ws = (char*)d_ws;
    float*    o1   = (float*)ws;                          // 64N f32
    uint_t*   sp1  = (uint_t*)(ws + n * 256);             // 8N u32 (bf16x2 exp table)
    float*    ed1  = (float*)(ws + n * 288);              // 8N f32
    ushort_t* h1   = (ushort_t*)(ws + n * 320);           // 64N bf16
    uint_t*   pk   = (uint_t*)(ws + n * 448);             // (E+N) uint
    char*     tail = ws + n * 448 + (size_t)(E + N) * 4;
    int*      bcnt = (int*)tail;                          // NBMAX int
    int*      boff = (int*)(tail + NBMAX * 4);            // NBMAX int
    int*      bcur = (int*)(tail + NBMAX * 8);            // NBMAX int
    float*  pooled = (float*)(tail + NBMAX * 12);         // 1 f32
    // layer-2 overlays (regions dead after edge1):
    ushort_t* h2  = h1;              // 32N bf16
    uint_t*   sp2 = sp1;             // N u32
    float*    ed2 = ed1;             // N f32

    zerob_kernel<<<8, 256, 0, stream>>>(bcnt, NB, pooled);
    gemm1_kernel<<<(N + 15) / 16, 256, 0, stream>>>(x, W1, a_s1, a_d1, h1, sp1, ed1, N);
    bhist_kernel<<<256, 256, 0, stream>>>(ei, E, N, bcnt, NB);
    bscan_kernel<<<1, 64, 0, stream>>>(bcnt, NB, boff, bcur);
    bscat_kernel<<<256, 256, 0, stream>>>(ei, E, N, bcur, pk, NB);
    edge1_gather<<<NB, 256, 0, stream>>>(bcnt, boff, pk, sp1, ed1, h1, o1, N);
    gemm2_kernel<<<(N + 7) / 8, 256, 0, stream>>>(o1, b1, W2, a_s2, a_d2, h2, sp2, ed2, N);
    edge2_gather<<<NB, 256, 0, stream>>>(bcnt, boff, pk, sp2, ed2, h2, b2, Wr, pooled, N);
    final_kernel<<<1, 64, 0, stream>>>(pooled, br, out);
}